// Round 1
// baseline (454.009 us; speedup 1.0000x reference)
//
#include <hip/hip_runtime.h>
#include <hip/hip_bf16.h>
#include <cstdint>

// Problem constants (from reference setup_inputs)
#define B_DIM 16384
#define DX 256
#define DH 512
#define DS 128
#define DT 128
#define KDIM 1024   // DX+DH+DS+DT
#define NDIM 2048   // 4*DH (gate-interleaved packed order: n = h*4 + g)
#define HOUT 512

typedef __attribute__((ext_vector_type(8))) short short8;
typedef __attribute__((ext_vector_type(4))) float floatx4;

// ---------------------------------------------------------------------------
// pack_A: concat [x | h | spatial | temporal] rows -> bf16 [B_DIM][KDIM]
// 2 elements per thread, coalesced reads/writes. Segment boundaries all even.
// ---------------------------------------------------------------------------
__global__ __launch_bounds__(256) void pack_A(
    const float* __restrict__ x, const float* __restrict__ h,
    const float* __restrict__ s, const float* __restrict__ t,
    __hip_bfloat16* __restrict__ Ap) {
  int tidg = blockIdx.x * 256 + threadIdx.x;  // 0 .. B_DIM*KDIM/2 - 1
  int b = tidg >> 9;                          // KDIM/2 = 512 pairs per row
  int k = (tidg & 511) * 2;
  float a0, a1;
  if (k < 256)      { const float* p = x + (size_t)b * DX + k;         a0 = p[0]; a1 = p[1]; }
  else if (k < 768) { const float* p = h + (size_t)b * DH + (k - 256); a0 = p[0]; a1 = p[1]; }
  else if (k < 896) { const float* p = s + (size_t)b * DS + (k - 768); a0 = p[0]; a1 = p[1]; }
  else              { const float* p = t + (size_t)b * DT + (k - 896); a0 = p[0]; a1 = p[1]; }
  __hip_bfloat162 v;
  v.x = __float2bfloat16(a0);
  v.y = __float2bfloat16(a1);
  *reinterpret_cast<__hip_bfloat162*>(Ap + (size_t)b * KDIM + k) = v;
}

// ---------------------------------------------------------------------------
// pack_W: concat [W_x; W_h; W_s; W_t] -> bf16 Wt[NDIM][KDIM] (transposed,
// k-contiguous rows for MFMA B-fragment ds_read_b128) with gate interleave:
// packed n = h*4 + g  <->  original col c = g*512 + h.
// Reads are strided but the 8 MB source lives in L2/L3; writes coalesced.
// ---------------------------------------------------------------------------
__global__ __launch_bounds__(256) void pack_W(
    const float* __restrict__ Wx, const float* __restrict__ Wh,
    const float* __restrict__ Ws, const float* __restrict__ Wt,
    __hip_bfloat16* __restrict__ Wp) {
  int idx = blockIdx.x * 256 + threadIdx.x;  // 0 .. NDIM*KDIM - 1
  int n = idx >> 10;                         // KDIM = 1024
  int k = idx & 1023;
  int c = ((n & 3) << 9) | (n >> 2);         // g*512 + h
  float v;
  if (k < 256)      v = Wx[(size_t)k * NDIM + c];
  else if (k < 768) v = Wh[(size_t)(k - 256) * NDIM + c];
  else if (k < 896) v = Ws[(size_t)(k - 768) * NDIM + c];
  else              v = Wt[(size_t)(k - 896) * NDIM + c];
  Wp[(size_t)n * KDIM + k] = __float2bfloat16(v);
}

// ---------------------------------------------------------------------------
// Fused GEMM + LSTM epilogue.
// 128x128 output tile per 256-thread block (2x2 waves, each 64x64 = 4x4 MFMA
// tiles of 16x16x32 bf16). BK=32, global_load_lds width=16 staging.
// Block's 128 packed cols = 32 hidden units x 4 gates -> epilogue in-block.
// LDS: staging (8KB A + 8KB B) union'd with 128x132 fp32 preact tile (67.5KB).
// ---------------------------------------------------------------------------
__global__ __launch_bounds__(256, 2) void lstm_gemm(
    const __hip_bfloat16* __restrict__ Ap, const __hip_bfloat16* __restrict__ Wp,
    const float* __restrict__ bh, const float* __restrict__ c_in,
    float* __restrict__ out) {
  __shared__ union {
    struct { unsigned short A[128 * 32]; unsigned short B[128 * 32]; } s;
    float C[128 * 132];  // +4 pad per row: conflict-light epilogue reads
  } sm;

  const int tid = threadIdx.x;
  const int lane = tid & 63;
  const int wid = tid >> 6;
  const int wm = wid & 1;    // wave's 64-row half
  const int wn = wid >> 1;   // wave's 64-col half
  const int m0 = blockIdx.y * 128;
  const int n0 = blockIdx.x * 128;

  floatx4 acc[4][4];
#pragma unroll
  for (int i = 0; i < 4; ++i)
#pragma unroll
    for (int j = 0; j < 4; ++j) acc[i][j] = (floatx4)0.f;

  // global_load_lds addressing: dest = wave-uniform base + lane*16B, so the
  // LDS tile is exactly row-major [128][32] bf16 (no padding) and lane i of
  // chunk covers row chunk*16 + i/4, k-octet (i%4)*8.
  const int ldrow = lane >> 2;
  const int ldk = (lane & 3) * 8;
  // MFMA fragment addressing (16x16x32): m/n = lane&15, k = (lane>>4)*8 + j
  const int fr = lane & 15;
  const int fk = (lane >> 4) * 8;

  for (int kt = 0; kt < KDIM; kt += 32) {
#pragma unroll
    for (int j = 0; j < 2; ++j) {
      const int chunk = wid * 2 + j;         // wave-uniform
      const int row = chunk * 16 + ldrow;
      const __hip_bfloat16* ga = Ap + (size_t)(m0 + row) * KDIM + kt + ldk;
      __builtin_amdgcn_global_load_lds(
          (const __attribute__((address_space(1))) void*)ga,
          (__attribute__((address_space(3))) void*)&sm.s.A[chunk * 512], 16, 0, 0);
      const __hip_bfloat16* gb = Wp + (size_t)(n0 + row) * KDIM + kt + ldk;
      __builtin_amdgcn_global_load_lds(
          (const __attribute__((address_space(1))) void*)gb,
          (__attribute__((address_space(3))) void*)&sm.s.B[chunk * 512], 16, 0, 0);
    }
    __syncthreads();  // drains vmcnt before barrier (compiler-enforced)

    short8 af[4], bf[4];
#pragma unroll
    for (int i = 0; i < 4; ++i) {
      af[i] = *(const short8*)&sm.s.A[(wm * 64 + i * 16 + fr) * 32 + fk];
      bf[i] = *(const short8*)&sm.s.B[(wn * 64 + i * 16 + fr) * 32 + fk];
    }
#pragma unroll
    for (int mi = 0; mi < 4; ++mi)
#pragma unroll
      for (int ni = 0; ni < 4; ++ni)
        acc[mi][ni] = __builtin_amdgcn_mfma_f32_16x16x32_bf16(
            af[mi], bf[ni], acc[mi][ni], 0, 0, 0);
    __syncthreads();  // all waves done reading staging before reuse / C-write
  }

  // Spill accumulators to LDS preact tile.
  // C/D layout (verified m89/m91): col = lane&15, row = (lane>>4)*4 + reg.
#pragma unroll
  for (int mi = 0; mi < 4; ++mi) {
    const int rbase = wm * 64 + mi * 16 + (lane >> 4) * 4;
#pragma unroll
    for (int ni = 0; ni < 4; ++ni) {
      const int col = wn * 64 + ni * 16 + fr;
#pragma unroll
      for (int r = 0; r < 4; ++r)
        sm.C[(rbase + r) * 132 + col] = acc[mi][ni][r];
    }
  }
  __syncthreads();

  // Epilogue: 4 threads per row, each handles 8 consecutive hidden units.
  // Packed col 4*h+g -> gates g: 0=i, 1=f, 2=o, 3=c~.
  const int r0 = tid >> 2;        // 0..63
  const int q = tid & 3;          // which 8-wide h slice
  const int hg0 = n0 >> 2;        // block's global hidden base (32 units)
#pragma unroll
  for (int half = 0; half < 2; ++half) {
    const int row = r0 + 64 * half;
    const size_t grow = (size_t)(m0 + row);
    const float* crow = c_in + grow * HOUT + hg0 + q * 8;
    floatx4 hn[2], cn[2];
#pragma unroll
    for (int jj = 0; jj < 8; ++jj) {
      const int hh = q * 8 + jj;
      const int hg = hg0 + hh;
      const float* pr = &sm.C[row * 132 + 4 * hh];
      const float p0 = pr[0] + bh[hg];
      const float p1 = pr[1] + bh[512 + hg];
      const float p2 = pr[2] + bh[1024 + hg];
      const float p3 = pr[3] + bh[1536 + hg];
      const float ig = 1.f / (1.f + __expf(-p0));
      const float fg = 1.f / (1.f + __expf(-p1));
      const float og = 1.f / (1.f + __expf(-p2));
      const float cg = tanhf(p3);
      const float cc = fg * crow[jj] + ig * cg;
      cn[jj >> 2][jj & 3] = cc;
      hn[jj >> 2][jj & 3] = tanhf(og * cc);  // faithful: tanh(o * c_new)
    }
    float* oh = out + grow * HOUT + hg0 + q * 8;
    float* oc = out + (size_t)B_DIM * HOUT + grow * HOUT + hg0 + q * 8;
    *(floatx4*)(oh + 0) = hn[0];
    *(floatx4*)(oh + 4) = hn[1];
    *(floatx4*)(oc + 0) = cn[0];
    *(floatx4*)(oc + 4) = cn[1];
  }
}

// ---------------------------------------------------------------------------
extern "C" void kernel_launch(void* const* d_in, const int* in_sizes, int n_in,
                              void* d_out, int out_size, void* d_ws, size_t ws_size,
                              hipStream_t stream) {
  const float* x  = (const float*)d_in[0];
  const float* h  = (const float*)d_in[1];
  const float* c  = (const float*)d_in[2];
  const float* sp = (const float*)d_in[3];
  const float* tp = (const float*)d_in[4];
  const float* Wx = (const float*)d_in[5];
  const float* Wh = (const float*)d_in[6];
  const float* bh = (const float*)d_in[7];
  const float* Ws = (const float*)d_in[8];
  const float* Wt = (const float*)d_in[9];
  float* out = (float*)d_out;

  // Workspace: Apack bf16 [16384][1024] (32 MB) + Wpack bf16 [2048][1024] (4 MB)
  __hip_bfloat16* Ap = (__hip_bfloat16*)d_ws;
  __hip_bfloat16* Wp = (__hip_bfloat16*)((char*)d_ws + (size_t)B_DIM * KDIM * 2);

  pack_A<<<dim3((B_DIM * KDIM / 2) / 256), dim3(256), 0, stream>>>(x, h, sp, tp, Ap);
  pack_W<<<dim3((NDIM * KDIM) / 256), dim3(256), 0, stream>>>(Wx, Wh, Ws, Wt, Wp);
  lstm_gemm<<<dim3(NDIM / 128, B_DIM / 128), dim3(256), 0, stream>>>(Ap, Wp, bh, c, out);
}

// Round 3
// 256.564 us; speedup vs baseline: 1.7696x; 1.7696x over previous
//
#include <hip/hip_runtime.h>
#include <hip/hip_bf16.h>
#include <cstdint>

// Problem constants
#define B_DIM 16384
#define DX 256
#define DH 512
#define DS 128
#define DT 128
#define KDIM 1024   // DX+DH+DS+DT
#define NDIM 2048   // 4*DH
#define HOUT 512

typedef __attribute__((ext_vector_type(8))) short short8;
typedef __attribute__((ext_vector_type(4))) float floatx4;

union bf16x8 {
  short8 v;
  __hip_bfloat16 b[8];
};

__device__ __forceinline__ float fast_sigmoid(float x) {
  return 1.f / (1.f + __expf(-x));
}
__device__ __forceinline__ float fast_tanh(float x) {
  // tanh(x) = (1 - e^{-2x}) / (1 + e^{-2x}); no overflow for |x| < 40 (fp32)
  float e = __expf(-2.f * x);
  return (1.f - e) / (1.f + e);
}

// ---------------------------------------------------------------------------
// pack_A: concat [x | h | s | t] rows -> bf16 [B_DIM][KDIM]. 8 elem/thread,
// 2x float4 read + one 16B store. Segment boundaries (256/768/896) are all
// multiples of 8, so a thread's 8-chunk never crosses segments.
// ---------------------------------------------------------------------------
__global__ __launch_bounds__(256) void pack_A(
    const float* __restrict__ x, const float* __restrict__ h,
    const float* __restrict__ s, const float* __restrict__ t,
    __hip_bfloat16* __restrict__ Ap) {
  int tid = blockIdx.x * 256 + threadIdx.x;   // 0 .. B_DIM*KDIM/8 - 1
  int b = tid >> 7;                           // 128 octets per row
  int k = (tid & 127) * 8;
  const float* p;
  if (k < 256)      p = x + (size_t)b * DX + k;
  else if (k < 768) p = h + (size_t)b * DH + (k - 256);
  else if (k < 896) p = s + (size_t)b * DS + (k - 768);
  else              p = t + (size_t)b * DT + (k - 896);
  floatx4 v0 = *(const floatx4*)p;
  floatx4 v1 = *(const floatx4*)(p + 4);
  bf16x8 o;
#pragma unroll
  for (int j = 0; j < 4; ++j) {
    o.b[j]     = __float2bfloat16(v0[j]);
    o.b[4 + j] = __float2bfloat16(v1[j]);
  }
  *(short8*)(Ap + (size_t)b * KDIM + k) = o.v;
}

// ---------------------------------------------------------------------------
// pack_W: -> bf16 Wp[NDIM][KDIM], k-contiguous rows, packed col order
//   n = (hh/32)*128 + g*32 + (hh%32)   (hh = hidden unit, g = gate)
// inverse: nb=n>>7, g=(n>>5)&3, hl=n&31  ->  original col c = g*512 + nb*32 + hl.
// Thread = (n, k-octet): reads coalesced over c (consecutive n -> consecutive c
// within 32-blocks), writes one 16B chunk. k-octets never cross segments.
// ---------------------------------------------------------------------------
__global__ __launch_bounds__(256) void pack_W(
    const float* __restrict__ Wx, const float* __restrict__ Wh,
    const float* __restrict__ Ws, const float* __restrict__ Wt,
    __hip_bfloat16* __restrict__ Wp) {
  int t = blockIdx.x * 256 + threadIdx.x;     // 0 .. NDIM*128 - 1
  int n = t & (NDIM - 1);
  int k0 = (t >> 11) * 8;                     // 0..1016
  int g = (n >> 5) & 3, nb = n >> 7, hl = n & 31;
  int c = g * 512 + nb * 32 + hl;
  const float* src; int kl;
  if (k0 < 256)      { src = Wx; kl = k0; }
  else if (k0 < 768) { src = Wh; kl = k0 - 256; }
  else if (k0 < 896) { src = Ws; kl = k0 - 768; }
  else               { src = Wt; kl = k0 - 896; }
  bf16x8 o;
#pragma unroll
  for (int r = 0; r < 8; ++r)
    o.b[r] = __float2bfloat16(src[(size_t)(kl + r) * NDIM + c]);
  *(short8*)(Wp + (size_t)n * KDIM + k0) = o.v;
}

// ---------------------------------------------------------------------------
// Fused GEMM + in-register LSTM epilogue.
// 128x128 tile / 256-thread block. Waves split ROWS only: wave w = rows
// w*32..w*32+31 x all 128 cols -> acc[2][8] of 16x16x32 bf16 MFMA tiles.
// With the gate-plane packing, gate g of hidden hh lives at col-tile
// ni = 2g + hb (hb = (hh%32)/16) in the SAME lane/reg -> epilogue needs no
// LDS and no shuffles. LDS = 16 KB staging only.
// ---------------------------------------------------------------------------
__global__ __launch_bounds__(256, 4) void lstm_gemm(
    const __hip_bfloat16* __restrict__ Ap, const __hip_bfloat16* __restrict__ Wp,
    const float* __restrict__ bh, const float* __restrict__ c_in,
    float* __restrict__ out) {
  __shared__ unsigned short As[128 * 32];  // [row][k] bf16, 64 B rows
  __shared__ unsigned short Bs[128 * 32];  // [packed-col][k] bf16

  const int tid = threadIdx.x;
  const int lane = tid & 63;
  const int wid = tid >> 6;
  const int q = lane >> 4;     // quad-row group 0..3
  const int fr = lane & 15;
  const int fk = q * 8;
  const int m0 = blockIdx.y * 128;
  const int nb = blockIdx.x;   // hidden group (32 units)
  const int n0 = nb * 128;
  const int hg0 = nb * 32;

  floatx4 acc[2][8];
#pragma unroll
  for (int i = 0; i < 2; ++i)
#pragma unroll
    for (int j = 0; j < 8; ++j) acc[i][j] = (floatx4)0.f;

  const int ldrow = lane >> 2;        // staging: lane -> row within 16-row chunk
  const int ldk = (lane & 3) * 8;     // and k-octet

  for (int kt = 0; kt < KDIM; kt += 32) {
#pragma unroll
    for (int j = 0; j < 2; ++j) {
      const int chunk = wid * 2 + j;  // wave-uniform
      const int row = chunk * 16 + ldrow;
      const __hip_bfloat16* ga = Ap + (size_t)(m0 + row) * KDIM + kt + ldk;
      __builtin_amdgcn_global_load_lds(
          (const __attribute__((address_space(1))) void*)ga,
          (__attribute__((address_space(3))) void*)&As[chunk * 512], 16, 0, 0);
      const __hip_bfloat16* gb = Wp + (size_t)(n0 + row) * KDIM + kt + ldk;
      __builtin_amdgcn_global_load_lds(
          (const __attribute__((address_space(1))) void*)gb,
          (__attribute__((address_space(3))) void*)&Bs[chunk * 512], 16, 0, 0);
    }
    __syncthreads();

    short8 af[2];
#pragma unroll
    for (int mi = 0; mi < 2; ++mi)
      af[mi] = *(const short8*)&As[(wid * 32 + mi * 16 + fr) * 32 + fk];
#pragma unroll
    for (int half = 0; half < 2; ++half) {
      short8 bf[4];
#pragma unroll
      for (int ni = 0; ni < 4; ++ni)
        bf[ni] = *(const short8*)&Bs[((half * 4 + ni) * 16 + fr) * 32 + fk];
#pragma unroll
      for (int mi = 0; mi < 2; ++mi)
#pragma unroll
        for (int ni = 0; ni < 4; ++ni)
          acc[mi][half * 4 + ni] = __builtin_amdgcn_mfma_f32_16x16x32_bf16(
              af[mi], bf[ni], acc[mi][half * 4 + ni], 0, 0, 0);
    }
    __syncthreads();
  }

  // ---- In-register epilogue ----
  // acc[mi][ni] tile: rows wid*32+mi*16 + (q*4+r), col-local ni*16+fr.
  // col-local = g*32 + hb*16 + fr  ->  ni = 2g + hb, hh = hg0 + hb*16 + fr.
  float bias[2][4];
#pragma unroll
  for (int hb = 0; hb < 2; ++hb) {
    const int hh = hg0 + hb * 16 + fr;
#pragma unroll
    for (int g = 0; g < 4; ++g) bias[hb][g] = bh[g * 512 + hh];
  }

#pragma unroll
  for (int mi = 0; mi < 2; ++mi) {
    const int rowl = wid * 32 + mi * 16 + q * 4;
#pragma unroll
    for (int r = 0; r < 4; ++r) {
      const size_t grow = (size_t)(m0 + rowl + r);
#pragma unroll
      for (int hb = 0; hb < 2; ++hb) {
        const int hh = hg0 + hb * 16 + fr;
        const float pi = acc[mi][0 + hb][r] + bias[hb][0];
        const float pf = acc[mi][2 + hb][r] + bias[hb][1];
        const float po = acc[mi][4 + hb][r] + bias[hb][2];
        const float pc = acc[mi][6 + hb][r] + bias[hb][3];
        const float ig = fast_sigmoid(pi);
        const float fg = fast_sigmoid(pf);
        const float og = fast_sigmoid(po);
        const float cg = fast_tanh(pc);
        const float cc = fg * c_in[grow * HOUT + hh] + ig * cg;
        out[grow * HOUT + hh] = fast_tanh(og * cc);  // faithful: tanh(o*c_new)
        out[(size_t)B_DIM * HOUT + grow * HOUT + hh] = cc;
      }
    }
  }
}

// ---------------------------------------------------------------------------
extern "C" void kernel_launch(void* const* d_in, const int* in_sizes, int n_in,
                              void* d_out, int out_size, void* d_ws, size_t ws_size,
                              hipStream_t stream) {
  const float* x  = (const float*)d_in[0];
  const float* h  = (const float*)d_in[1];
  const float* c  = (const float*)d_in[2];
  const float* sp = (const float*)d_in[3];
  const float* tp = (const float*)d_in[4];
  const float* Wx = (const float*)d_in[5];
  const float* Wh = (const float*)d_in[6];
  const float* bh = (const float*)d_in[7];
  const float* Ws = (const float*)d_in[8];
  const float* Wt = (const float*)d_in[9];
  float* out = (float*)d_out;

  __hip_bfloat16* Ap = (__hip_bfloat16*)d_ws;                                     // 32 MB
  __hip_bfloat16* Wp = (__hip_bfloat16*)((char*)d_ws + (size_t)B_DIM * KDIM * 2); // 4 MB

  pack_A<<<dim3(B_DIM * KDIM / 8 / 256), dim3(256), 0, stream>>>(x, h, sp, tp, Ap);
  pack_W<<<dim3(NDIM * 128 / 256), dim3(256), 0, stream>>>(Wx, Wh, Ws, Wt, Wp);
  lstm_gemm<<<dim3(NDIM / 128, B_DIM / 128), dim3(256), 0, stream>>>(Ap, Wp, bh, c, out);
}

// Round 4
// 251.365 us; speedup vs baseline: 1.8062x; 1.0207x over previous
//
#include <hip/hip_runtime.h>
#include <hip/hip_bf16.h>
#include <cstdint>

// Problem constants
#define B_DIM 16384
#define DX 256
#define DH 512
#define DS 128
#define DT 128
#define KDIM 1024   // DX+DH+DS+DT
#define NDIM 2048   // 4*DH
#define HOUT 512

typedef __attribute__((ext_vector_type(8))) short short8;
typedef __attribute__((ext_vector_type(4))) float floatx4;

union bf16x8 {
  short8 v;
  __hip_bfloat16 b[8];
};

__device__ __forceinline__ float fast_sigmoid(float x) {
  return 1.f / (1.f + __expf(-x));
}
__device__ __forceinline__ float fast_tanh(float x) {
  float e = __expf(-2.f * x);
  return (1.f - e) / (1.f + e);
}

// ===========================================================================
// Tiled operand layouts (we own both, so stage-ready chunk order):
//   A tile (mb,kb) = 128 rows x 64 k, stored as 16 chunks of 512 bf16.
//   chunk t = s*8 + c  (s = 32-k panel, c = 16-row group)
//   chunk-lane i: row = c*16 + i/4, k = kb*64 + s*32 + (i&3)*8 (+j, j=0..7)
//   flat elem index = ((mb*16 + kb)*16 + t)*512 + i*8 + j
// Same for W over packed columns, with packed col order
//   n_local = wn*64 + g*16 + hl  <->  hidden hh = nblk*32 + wn*16 + hl,
//   original weight col = g*512 + hh   (gate g: 0=i,1=f,2=o,3=c~)
// ===========================================================================

// ---------------------------------------------------------------------------
// pack_A: [x|h|s|t] fp32 -> bf16 tiled Ap. 1 dest octet (16B) per thread,
// stores perfectly contiguous; reads 32B from one source row.
// ---------------------------------------------------------------------------
__global__ __launch_bounds__(256) void pack_A(
    const float* __restrict__ x, const float* __restrict__ h,
    const float* __restrict__ s, const float* __restrict__ t,
    __hip_bfloat16* __restrict__ Ap) {
  int tid = blockIdx.x * 256 + threadIdx.x;  // 0 .. B_DIM*KDIM/8-1 (2,097,152)
  int i = tid & 63;
  int tt = (tid >> 6) & 15;
  int tile = tid >> 10;          // mb*16 + kb
  int kb = tile & 15, mb = tile >> 4;
  int sp = tt >> 3, c = tt & 7;
  int b = mb * 128 + c * 16 + (i >> 2);
  int k = kb * 64 + sp * 32 + (i & 3) * 8;
  const float* p;
  if (k < 256)      p = x + (size_t)b * DX + k;
  else if (k < 768) p = h + (size_t)b * DH + (k - 256);
  else if (k < 896) p = s + (size_t)b * DS + (k - 768);
  else              p = t + (size_t)b * DT + (k - 896);
  floatx4 v0 = *(const floatx4*)p;
  floatx4 v1 = *(const floatx4*)(p + 4);
  bf16x8 o;
#pragma unroll
  for (int j = 0; j < 4; ++j) {
    o.b[j]     = __float2bfloat16(v0[j]);
    o.b[4 + j] = __float2bfloat16(v1[j]);
  }
  *(short8*)(Ap + (size_t)tid * 8) = o.v;
}

// ---------------------------------------------------------------------------
// pack_W: [W_x;W_h;W_s;W_t] fp32 -> bf16 tiled Wp (packed-col order above).
// 1 dest octet per thread (contiguous stores); 8 strided source reads
// (8 KB apart) — 12 MB total, L2/L3 resident, ~few µs.
// ---------------------------------------------------------------------------
__global__ __launch_bounds__(256) void pack_W(
    const float* __restrict__ Wx, const float* __restrict__ Wh,
    const float* __restrict__ Ws, const float* __restrict__ Wt,
    __hip_bfloat16* __restrict__ Wp) {
  int tid = blockIdx.x * 256 + threadIdx.x;  // 0 .. NDIM*KDIM/8-1 (262,144)
  int i = tid & 63;
  int tt = (tid >> 6) & 15;
  int tile = tid >> 10;          // nblk*16 + kb
  int kb = tile & 15, nblk = tile >> 4;
  int sp = tt >> 3, c = tt & 7;
  int nl = c * 16 + (i >> 2);    // local packed col 0..127
  int k = kb * 64 + sp * 32 + (i & 3) * 8;
  int wn = nl >> 6, g = (nl >> 4) & 3, hl = nl & 15;
  int col = g * 512 + nblk * 32 + wn * 16 + hl;
  const float* src; int kl;
  if (k < 256)      { src = Wx; kl = k; }
  else if (k < 768) { src = Wh; kl = k - 256; }
  else if (k < 896) { src = Ws; kl = k - 768; }
  else              { src = Wt; kl = k - 896; }
  bf16x8 o;
#pragma unroll
  for (int r = 0; r < 8; ++r)
    o.b[r] = __float2bfloat16(src[(size_t)(kl + r) * NDIM + col]);
  *(short8*)(Wp + (size_t)tid * 8) = o.v;
}

// ---------------------------------------------------------------------------
// Fused GEMM + in-register LSTM epilogue.
// 128x128 tile, 2x2 waves (64x64/wave, 4x4 16x16x32 MFMA tiles). BK=64 as
// two 32-k panels. A staged via global_load_lds (16 KB LDS total);
// B fragments loaded DIRECTLY from global (L2-resident 4 MB Wp; tiled layout
// makes each frag a coalesced 1 KB wave read) — no LDS writes or reads for B.
// Gates live on the wave's 4 col-tiles -> epilogue fully in-register.
// ---------------------------------------------------------------------------
__global__ __launch_bounds__(256, 3) void lstm_gemm(
    const __hip_bfloat16* __restrict__ Ap, const __hip_bfloat16* __restrict__ Wp,
    const float* __restrict__ bh, const float* __restrict__ c_in,
    float* __restrict__ out) {
  __shared__ unsigned short As[2 * 128 * 32];  // 16 KB: [panel][row][32k]

  const int tid = threadIdx.x;
  const int lane = tid & 63;
  const int wid = tid >> 6;
  const int wm = wid & 1;        // row half (64 rows)
  const int wn = wid >> 1;       // col half (64 packed cols)
  const int q = lane >> 4;
  const int fr = lane & 15;
  const int mb = blockIdx.y;
  const int nblk = blockIdx.x;
  const int m0 = mb * 128;

  floatx4 acc[4][4];
#pragma unroll
  for (int i = 0; i < 4; ++i)
#pragma unroll
    for (int j = 0; j < 4; ++j) acc[i][j] = (floatx4)0.f;

  const int blane = (fr * 4 + q) * 8;  // chunk-lane offset for B frag reads

  for (int kt = 0; kt < KDIM / 64; ++kt) {
    // --- stage A tile (16 chunks, 4 per wave), lane-contiguous global reads
    const size_t abase = ((size_t)(mb * 16 + kt) * 16) * 512;
#pragma unroll
    for (int j = 0; j < 4; ++j) {
      const int chunk = wid * 4 + j;
      __builtin_amdgcn_global_load_lds(
          (const __attribute__((address_space(1))) void*)
              (Ap + abase + (size_t)chunk * 512 + lane * 8),
          (__attribute__((address_space(3))) void*)&As[chunk * 512], 16, 0, 0);
    }
    // --- B fragments straight from global (independent of LDS), in flight
    //     during the barrier's vmcnt drain
    short8 bf[2][4];
    const size_t bbase = ((size_t)(nblk * 16 + kt) * 16) * 512;
#pragma unroll
    for (int sp = 0; sp < 2; ++sp)
#pragma unroll
      for (int ni = 0; ni < 4; ++ni)
        bf[sp][ni] = *(const short8*)(Wp + bbase +
                         (size_t)(sp * 8 + wn * 4 + ni) * 512 + blane);
    __syncthreads();

#pragma unroll
    for (int sp = 0; sp < 2; ++sp) {
      short8 af[4];
#pragma unroll
      for (int mi = 0; mi < 4; ++mi)
        af[mi] = *(const short8*)&As[sp * 4096 +
                                     (wm * 64 + mi * 16 + fr) * 32 + q * 8];
#pragma unroll
      for (int mi = 0; mi < 4; ++mi)
#pragma unroll
        for (int ni = 0; ni < 4; ++ni)
          acc[mi][ni] = __builtin_amdgcn_mfma_f32_16x16x32_bf16(
              af[mi], bf[sp][ni], acc[mi][ni], 0, 0, 0);
    }
    __syncthreads();
  }

  // ---- In-register epilogue ----
  // acc[mi][g]: rows wm*64+mi*16+q*4+r, gate g of hidden hh (col-tile = gate).
  const int hh = nblk * 32 + wn * 16 + fr;
  float bias[4];
#pragma unroll
  for (int g = 0; g < 4; ++g) bias[g] = bh[g * 512 + hh];

#pragma unroll
  for (int mi = 0; mi < 4; ++mi) {
#pragma unroll
    for (int r = 0; r < 4; ++r) {
      const size_t grow = (size_t)(m0 + wm * 64 + mi * 16 + q * 4 + r);
      const float pi = acc[mi][0][r] + bias[0];
      const float pf = acc[mi][1][r] + bias[1];
      const float po = acc[mi][2][r] + bias[2];
      const float pc = acc[mi][3][r] + bias[3];
      const float ig = fast_sigmoid(pi);
      const float fg = fast_sigmoid(pf);
      const float og = fast_sigmoid(po);
      const float cg = fast_tanh(pc);
      const float cc = fg * c_in[grow * HOUT + hh] + ig * cg;
      out[grow * HOUT + hh] = fast_tanh(og * cc);  // faithful: tanh(o*c_new)
      out[(size_t)B_DIM * HOUT + grow * HOUT + hh] = cc;
    }
  }
}

// ---------------------------------------------------------------------------
extern "C" void kernel_launch(void* const* d_in, const int* in_sizes, int n_in,
                              void* d_out, int out_size, void* d_ws, size_t ws_size,
                              hipStream_t stream) {
  const float* x  = (const float*)d_in[0];
  const float* h  = (const float*)d_in[1];
  const float* c  = (const float*)d_in[2];
  const float* sp = (const float*)d_in[3];
  const float* tp = (const float*)d_in[4];
  const float* Wx = (const float*)d_in[5];
  const float* Wh = (const float*)d_in[6];
  const float* bh = (const float*)d_in[7];
  const float* Ws = (const float*)d_in[8];
  const float* Wt = (const float*)d_in[9];
  float* out = (float*)d_out;

  __hip_bfloat16* Ap = (__hip_bfloat16*)d_ws;                                     // 32 MB
  __hip_bfloat16* Wp = (__hip_bfloat16*)((char*)d_ws + (size_t)B_DIM * KDIM * 2); // 4 MB

  pack_A<<<dim3(B_DIM * KDIM / 8 / 256), dim3(256), 0, stream>>>(x, h, sp, tp, Ap);
  pack_W<<<dim3(NDIM * KDIM / 8 / 256), dim3(256), 0, stream>>>(Wx, Wh, Ws, Wt, Wp);
  lstm_gemm<<<dim3(NDIM / 128, B_DIM / 128), dim3(256), 0, stream>>>(Ap, Wp, bh, c, out);
}

// Round 5
// 242.617 us; speedup vs baseline: 1.8713x; 1.0361x over previous
//
#include <hip/hip_runtime.h>
#include <hip/hip_bf16.h>
#include <cstdint>

// Problem constants
#define B_DIM 16384
#define DX 256
#define DH 512
#define DS 128
#define DT 128
#define KDIM 1024   // DX+DH+DS+DT
#define NDIM 2048   // 4*DH
#define HOUT 512

typedef __attribute__((ext_vector_type(8))) short short8;
typedef __attribute__((ext_vector_type(4))) float floatx4;

union bf16x8 {
  short8 v;
  __hip_bfloat16 b[8];
};

__device__ __forceinline__ float fast_sigmoid(float x) {
  return 1.f / (1.f + __expf(-x));
}
__device__ __forceinline__ float fast_tanh(float x) {
  float e = __expf(-2.f * x);
  return (1.f - e) / (1.f + e);
}

// ===========================================================================
// Tiled operand layouts (stage-ready chunk order):
//   A tile (mb,kb) = 128 rows x 64 k, 16 chunks of 512 bf16.
//   chunk t = s*8 + c  (s = 32-k panel, c = 16-row group)
//   chunk-lane i: row = c*16 + i/4, k = kb*64 + s*32 + (i&3)*8 (+j)
//   flat = ((mb*16 + kb)*16 + t)*512 + i*8 + j
// W identical over packed cols; packed col order
//   n_local = wn*64 + g*16 + hl  <->  hh = nblk*32 + wn*16 + hl,
//   original col = g*512 + hh    (g: 0=i,1=f,2=o,3=c~)
// ===========================================================================

__global__ __launch_bounds__(256) void pack_A(
    const float* __restrict__ x, const float* __restrict__ h,
    const float* __restrict__ s, const float* __restrict__ t,
    __hip_bfloat16* __restrict__ Ap) {
  int tid = blockIdx.x * 256 + threadIdx.x;  // 0 .. B_DIM*KDIM/8-1
  int i = tid & 63;
  int tt = (tid >> 6) & 15;
  int tile = tid >> 10;          // mb*16 + kb
  int kb = tile & 15, mb = tile >> 4;
  int sp = tt >> 3, c = tt & 7;
  int b = mb * 128 + c * 16 + (i >> 2);
  int k = kb * 64 + sp * 32 + (i & 3) * 8;
  const float* p;
  if (k < 256)      p = x + (size_t)b * DX + k;
  else if (k < 768) p = h + (size_t)b * DH + (k - 256);
  else if (k < 896) p = s + (size_t)b * DS + (k - 768);
  else              p = t + (size_t)b * DT + (k - 896);
  floatx4 v0 = *(const floatx4*)p;
  floatx4 v1 = *(const floatx4*)(p + 4);
  bf16x8 o;
#pragma unroll
  for (int j = 0; j < 4; ++j) {
    o.b[j]     = __float2bfloat16(v0[j]);
    o.b[4 + j] = __float2bfloat16(v1[j]);
  }
  *(short8*)(Ap + (size_t)tid * 8) = o.v;
}

__global__ __launch_bounds__(256) void pack_W(
    const float* __restrict__ Wx, const float* __restrict__ Wh,
    const float* __restrict__ Ws, const float* __restrict__ Wt,
    __hip_bfloat16* __restrict__ Wp) {
  int tid = blockIdx.x * 256 + threadIdx.x;  // 0 .. NDIM*KDIM/8-1
  int i = tid & 63;
  int tt = (tid >> 6) & 15;
  int tile = tid >> 10;          // nblk*16 + kb
  int kb = tile & 15, nblk = tile >> 4;
  int sp = tt >> 3, c = tt & 7;
  int nl = c * 16 + (i >> 2);    // local packed col 0..127
  int k = kb * 64 + sp * 32 + (i & 3) * 8;
  int wn = nl >> 6, g = (nl >> 4) & 3, hl = nl & 15;
  int col = g * 512 + nblk * 32 + wn * 16 + hl;
  const float* src; int kl;
  if (k < 256)      { src = Wx; kl = k; }
  else if (k < 768) { src = Wh; kl = k - 256; }
  else if (k < 896) { src = Ws; kl = k - 768; }
  else              { src = Wt; kl = k - 896; }
  bf16x8 o;
#pragma unroll
  for (int r = 0; r < 8; ++r)
    o.b[r] = __float2bfloat16(src[(size_t)(kl + r) * NDIM + col]);
  *(short8*)(Wp + (size_t)tid * 8) = o.v;
}

// ---------------------------------------------------------------------------
// m97-faithful K-loop + in-register LSTM epilogue.
// 128x128 tile, 2x2 waves, 4x4 16x16x32 MFMA acc/wave, BK=32, both operands
// via global_load_lds width=16 into 16 KB LDS, 2 barriers/iter.
// Gate g of hidden hh lives at the wave's col-tile ni=g -> register epilogue.
// ---------------------------------------------------------------------------
__global__ __launch_bounds__(256, 4) void lstm_gemm(
    const __hip_bfloat16* __restrict__ Ap, const __hip_bfloat16* __restrict__ Wp,
    const float* __restrict__ bh, const float* __restrict__ c_in,
    float* __restrict__ out) {
  __shared__ unsigned short As[128 * 32];  // 8 KB: [row][32k]
  __shared__ unsigned short Bs[128 * 32];  // 8 KB: [packed-col][32k]

  const int tid = threadIdx.x;
  const int lane = tid & 63;
  const int wid = tid >> 6;
  const int wm = wid & 1;        // row half (64 rows)
  const int wn = wid >> 1;       // col half (64 packed cols)
  const int q = lane >> 4;
  const int fr = lane & 15;
  const int mb = blockIdx.y;
  const int nblk = blockIdx.x;
  const int m0 = mb * 128;

  floatx4 acc[4][4];
#pragma unroll
  for (int i = 0; i < 4; ++i)
#pragma unroll
    for (int j = 0; j < 4; ++j) acc[i][j] = (floatx4)0.f;

  for (int p = 0; p < 32; ++p) {          // 32-k panels
    // tile kb = p>>1, panel s = p&1; 8 chunks of 512 bf16 each for A and B
    const size_t abase = ((size_t)((mb * 16 + (p >> 1)) * 16 + (p & 1) * 8)) * 512;
    const size_t bbase = ((size_t)((nblk * 16 + (p >> 1)) * 16 + (p & 1) * 8)) * 512;
#pragma unroll
    for (int j = 0; j < 2; ++j) {
      const int chunk = wid * 2 + j;      // wave-uniform, 0..7
      __builtin_amdgcn_global_load_lds(
          (const __attribute__((address_space(1))) void*)
              (Ap + abase + (size_t)chunk * 512 + lane * 8),
          (__attribute__((address_space(3))) void*)&As[chunk * 512], 16, 0, 0);
      __builtin_amdgcn_global_load_lds(
          (const __attribute__((address_space(1))) void*)
              (Wp + bbase + (size_t)chunk * 512 + lane * 8),
          (__attribute__((address_space(3))) void*)&Bs[chunk * 512], 16, 0, 0);
    }
    __syncthreads();

    short8 af[4], bf[4];
#pragma unroll
    for (int i = 0; i < 4; ++i) {
      af[i] = *(const short8*)&As[(wm * 64 + i * 16 + fr) * 32 + q * 8];
      bf[i] = *(const short8*)&Bs[(wn * 64 + i * 16 + fr) * 32 + q * 8];
    }
#pragma unroll
    for (int mi = 0; mi < 4; ++mi)
#pragma unroll
      for (int ni = 0; ni < 4; ++ni)
        acc[mi][ni] = __builtin_amdgcn_mfma_f32_16x16x32_bf16(
            af[mi], bf[ni], acc[mi][ni], 0, 0, 0);
    __syncthreads();
  }

  // ---- In-register epilogue ----
  // acc[mi][g]: rows wm*64+mi*16+q*4+r, gate g of hidden hh.
  const int hh = nblk * 32 + wn * 16 + fr;
  float bias[4];
#pragma unroll
  for (int g = 0; g < 4; ++g) bias[g] = bh[g * 512 + hh];

#pragma unroll
  for (int mi = 0; mi < 4; ++mi) {
#pragma unroll
    for (int r = 0; r < 4; ++r) {
      const size_t grow = (size_t)(m0 + wm * 64 + mi * 16 + q * 4 + r);
      const float pi = acc[mi][0][r] + bias[0];
      const float pf = acc[mi][1][r] + bias[1];
      const float po = acc[mi][2][r] + bias[2];
      const float pc = acc[mi][3][r] + bias[3];
      const float ig = fast_sigmoid(pi);
      const float fg = fast_sigmoid(pf);
      const float og = fast_sigmoid(po);
      const float cg = fast_tanh(pc);
      const float cc = fg * c_in[grow * HOUT + hh] + ig * cg;
      out[grow * HOUT + hh] = fast_tanh(og * cc);  // faithful: tanh(o*c_new)
      out[(size_t)B_DIM * HOUT + grow * HOUT + hh] = cc;
    }
  }
}

// ---------------------------------------------------------------------------
extern "C" void kernel_launch(void* const* d_in, const int* in_sizes, int n_in,
                              void* d_out, int out_size, void* d_ws, size_t ws_size,
                              hipStream_t stream) {
  const float* x  = (const float*)d_in[0];
  const float* h  = (const float*)d_in[1];
  const float* c  = (const float*)d_in[2];
  const float* sp = (const float*)d_in[3];
  const float* tp = (const float*)d_in[4];
  const float* Wx = (const float*)d_in[5];
  const float* Wh = (const float*)d_in[6];
  const float* bh = (const float*)d_in[7];
  const float* Ws = (const float*)d_in[8];
  const float* Wt = (const float*)d_in[9];
  float* out = (float*)d_out;

  __hip_bfloat16* Ap = (__hip_bfloat16*)d_ws;                                     // 32 MB
  __hip_bfloat16* Wp = (__hip_bfloat16*)((char*)d_ws + (size_t)B_DIM * KDIM * 2); // 4 MB

  pack_A<<<dim3(B_DIM * KDIM / 8 / 256), dim3(256), 0, stream>>>(x, h, sp, tp, Ap);
  pack_W<<<dim3(NDIM * KDIM / 8 / 256), dim3(256), 0, stream>>>(Wx, Wh, Ws, Wt, Wp);
  lstm_gemm<<<dim3(NDIM / 128, B_DIM / 128), dim3(256), 0, stream>>>(Ap, Wp, bh, c, out);
}